// Round 21
// baseline (115.700 us; speedup 1.0000x reference)
//
#include <hip/hip_runtime.h>
#include <hip/hip_bf16.h>
#include <math.h>

#define NPTS 50000
#define BATCH 2
#define CIN 64
#define C2 64
#define KNN 16
#define NCELL 125
#define MTOT 800000

// wsf layout (floats):
// [16..1552)    PART1: pass-1 partials (b*3+c)*256 + s*8 + blk
// [2048..3584)  PART2: pass-2 partials same indexing
// [8192..12192) packed dw table: 4000 uints
// [16384..316384)  xyzT[b*NPTS+n] float3 (1.2 MB)
// [327680..)    g[b][n][o] bf16 (12.8 MB)
// rel3 cache (19.2 MB, float3[b*MTOT+f]) lives in d_out (overwritten by kmain).

using bf16x8 = __attribute__((ext_vector_type(8))) short;
using f32x4  = __attribute__((ext_vector_type(4))) float;
using f32x2  = __attribute__((ext_vector_type(2))) float;

__device__ __forceinline__ f32x2 unpk(unsigned int v) {
    f32x2 r;
    r.x = __uint_as_float(v << 16);
    r.y = __uint_as_float(v & 0xffff0000u);
    return r;
}
__device__ __forceinline__ unsigned short f2bf(float f) {
    __hip_bfloat16 h = __float2bfloat16(f);
    return *(unsigned short*)&h;
}

__device__ __forceinline__ int to_cell32(float s) {
    float x = __fmul_rn(__fsub_rn(__fmul_rn(__fadd_rn(s, 1.0f), 5.0f), 1.0f), 0.5f);
    x = rintf(x);                       // half-to-even, matches np.round
    x = fminf(fmaxf(x, 0.0f), 4.0f);
    return (int)x;
}

// leaf bit-walk of numpy's pairwise split (n2 = n/2 - n/2%8), 8 levels, n=25000
__device__ __forceinline__ void leafwalk(int l, int& off, int& n) {
    off = 0; n = 25000;
    #pragma unroll
    for (int d = 7; d >= 0; --d) {
        int n2 = (n >> 1); n2 -= (n2 & 7);
        if ((l >> d) & 1) { off += n2; n -= n2; } else { n = n2; }
    }
}

// ---------------- K0: xyzT transpose (0..390) + dwpack (391..406) -----------
__global__ __launch_bounds__(256) void kprep(const float* __restrict__ xyz,
                                             const float* __restrict__ dw,
                                             float* __restrict__ wsf) {
    int bx = blockIdx.x;
    int t = threadIdx.x;
    if (bx < 391) {
        int gid = bx * 256 + t;
        if (gid < 2 * NPTS) {
            int b = (gid >= NPTS);
            int n = gid - b * NPTS;
            const float* xb = xyz + (size_t)b * 3 * NPTS;
            float3 v;
            v.x = xb[n]; v.y = xb[NPTS + n]; v.z = xb[2 * NPTS + n];
            ((float3*)(wsf + 16384))[gid] = v;
        }
    } else {
        unsigned int* gdwp = (unsigned int*)(wsf + 8192);
        int i0 = (bx - 391) * 250;
        for (int i = i0 + t; i < i0 + 250; i += 256) {
            int cell = i >> 5, u = i & 31;
            unsigned int p0 = f2bf(dw[(2 * u)     * NCELL + cell]);
            unsigned int p1 = f2bf(dw[(2 * u + 1) * NCELL + cell]);
            gdwp[i] = p0 | (p1 << 16);
        }
    }
}

// ---------------- K1: MFMA GEMM (0..1563, first) + pw1 tail (512) -----------
__global__ __launch_bounds__(256) void kfuse1(const int* __restrict__ knn,
                                              const float* __restrict__ fea,
                                              const float* __restrict__ W,
                                              unsigned short* __restrict__ g,
                                              float3* __restrict__ rel3,
                                              float* __restrict__ wsf) {
    __shared__ unsigned short flds[64 * 72];      // 9216B; pw1 aliases as lsum
    int bx = blockIdx.x;
    int t = threadIdx.x;
    if (bx < 1564) {
        // ---- MFMA GEMM: g[b][n][o] = sum_c W[o][c]*fea[b][c][n] -> bf16 ----
        int b = (bx >= 782);
        int tile = bx - b * 782;
        int n0 = tile * 64;
        int nrem = NPTS - n0; if (nrem > 64) nrem = 64;
        const float* fb = fea + (size_t)b * CIN * NPTS;
        int j = t & 63, w = t >> 6;
        int lane = t & 63, li = lane & 15, gq = lane >> 4;
        #pragma unroll
        for (int i = 0; i < 8; ++i) {
            int c = w * 2 + i * 8;
            float v0 = (j < nrem) ? fb[(size_t)c * NPTS + n0 + j] : 0.0f;
            float v1 = (j < nrem) ? fb[(size_t)(c + 1) * NPTS + n0 + j] : 0.0f;
            unsigned int pk = (unsigned int)f2bf(v0) | ((unsigned int)f2bf(v1) << 16);
            *(unsigned int*)&flds[j * 72 + c] = pk;
        }
        bf16x8 af[4][2];
        #pragma unroll
        for (int mt = 0; mt < 4; ++mt)
            #pragma unroll
            for (int kh = 0; kh < 2; ++kh) {
                const float* wp = W + (mt * 16 + li) * CIN + kh * 32 + gq * 8;
                float4 wa = *(const float4*)wp;
                float4 wb = *(const float4*)(wp + 4);
                bf16x8 a;
                a[0] = (short)f2bf(wa.x); a[1] = (short)f2bf(wa.y);
                a[2] = (short)f2bf(wa.z); a[3] = (short)f2bf(wa.w);
                a[4] = (short)f2bf(wb.x); a[5] = (short)f2bf(wb.y);
                a[6] = (short)f2bf(wb.z); a[7] = (short)f2bf(wb.w);
                af[mt][kh] = a;
            }
        __syncthreads();
        f32x4 acc[4];
        #pragma unroll
        for (int mt = 0; mt < 4; ++mt) acc[mt] = (f32x4){0.f, 0.f, 0.f, 0.f};
        #pragma unroll
        for (int kh = 0; kh < 2; ++kh) {
            bf16x8 bfv = *(const bf16x8*)&flds[(w * 16 + li) * 72 + kh * 32 + gq * 8];
            #pragma unroll
            for (int mt = 0; mt < 4; ++mt)
                acc[mt] = __builtin_amdgcn_mfma_f32_16x16x32_bf16(af[mt][kh], bfv,
                                                                  acc[mt], 0, 0, 0);
        }
        int nloc = w * 16 + li;
        if (nloc < nrem) {
            unsigned short* gr = g + ((size_t)b * NPTS + n0 + nloc) * C2;
            #pragma unroll
            for (int mt = 0; mt < 4; ++mt) {
                int ob = mt * 16 + gq * 4;
                uint2 pk;
                pk.x = (unsigned int)f2bf(acc[mt][0]) | ((unsigned int)f2bf(acc[mt][1]) << 16);
                pk.y = (unsigned int)f2bf(acc[mt][2]) | ((unsigned int)f2bf(acc[mt][3]) << 16);
                *(uint2*)(gr + ob) = pk;
            }
        }
    } else {
        // ---- pw1 tail (c-merged, unroll-4, xyzT float3 loads, rel3 store) --
        float* lsum = (float*)flds;
        const float3* xyzT = (const float3*)(wsf + 16384);
        int pid = bx - 1564;              // 0..511
        int b = pid >> 8, r8 = pid & 255;
        int s = r8 >> 3, blk = r8 & 7;
        const float3* xT = xyzT + (size_t)b * NPTS;
        const int* kb = knn + (size_t)b * NPTS * KNN;
        float3* relb = rel3 + (size_t)b * MTOT;
        int l = blk * 32 + (t >> 3);
        int j = t & 7;
        int off, n;
        leafwalk(l, off, n);
        int base = s * 25000 + off;
        float r0 = 0.0f, r1 = 0.0f, r2 = 0.0f;
        int i = j;
        for (; i + 24 < n; i += 32) {
            int f0 = base + i, f1 = f0 + 8, f2 = f0 + 16, f3 = f0 + 24;
            int kk0 = f0 / NPTS, nn0 = f0 - kk0 * NPTS;
            int kk1 = f1 / NPTS, nn1 = f1 - kk1 * NPTS;
            int kk2 = f2 / NPTS, nn2 = f2 - kk2 * NPTS;
            int kk3 = f3 / NPTS, nn3 = f3 - kk3 * NPTS;
            int jA = kb[nn0 * KNN + kk0];
            int jB = kb[nn1 * KNN + kk1];
            int jC = kb[nn2 * KNN + kk2];
            int jD = kb[nn3 * KNN + kk3];
            float3 cA = xT[nn0], nA = xT[jA];
            float3 cB = xT[nn1], nB = xT[jB];
            float3 cC = xT[nn2], nC = xT[jC];
            float3 cD = xT[nn3], nD = xT[jD];
            float3 vA, vB, vC, vD;
            vA.x = __fsub_rn(nA.x, cA.x); vA.y = __fsub_rn(nA.y, cA.y); vA.z = __fsub_rn(nA.z, cA.z);
            vB.x = __fsub_rn(nB.x, cB.x); vB.y = __fsub_rn(nB.y, cB.y); vB.z = __fsub_rn(nB.z, cB.z);
            vC.x = __fsub_rn(nC.x, cC.x); vC.y = __fsub_rn(nC.y, cC.y); vC.z = __fsub_rn(nC.z, cC.z);
            vD.x = __fsub_rn(nD.x, cD.x); vD.y = __fsub_rn(nD.y, cD.y); vD.z = __fsub_rn(nD.z, cD.z);
            relb[f0] = vA; relb[f1] = vB; relb[f2] = vC; relb[f3] = vD;
            // strict i-ascending accumulation per coord (bit-exact numpy chains)
            r0 = __fadd_rn(r0, vA.x); r1 = __fadd_rn(r1, vA.y); r2 = __fadd_rn(r2, vA.z);
            r0 = __fadd_rn(r0, vB.x); r1 = __fadd_rn(r1, vB.y); r2 = __fadd_rn(r2, vB.z);
            r0 = __fadd_rn(r0, vC.x); r1 = __fadd_rn(r1, vC.y); r2 = __fadd_rn(r2, vC.z);
            r0 = __fadd_rn(r0, vD.x); r1 = __fadd_rn(r1, vD.y); r2 = __fadd_rn(r2, vD.z);
        }
        for (; i < n; i += 8) {
            int f = base + i;
            int kk = f / NPTS, nn = f - kk * NPTS;
            int jj = kb[nn * KNN + kk];
            float3 cc = xT[nn], nv = xT[jj];
            float3 v;
            v.x = __fsub_rn(nv.x, cc.x); v.y = __fsub_rn(nv.y, cc.y); v.z = __fsub_rn(nv.z, cc.z);
            relb[f] = v;
            r0 = __fadd_rn(r0, v.x); r1 = __fadd_rn(r1, v.y); r2 = __fadd_rn(r2, v.z);
        }
        float a0 = __fadd_rn(r0, __shfl_xor(r0, 1));
        a0 = __fadd_rn(a0, __shfl_xor(a0, 2));
        a0 = __fadd_rn(a0, __shfl_xor(a0, 4));
        float a1 = __fadd_rn(r1, __shfl_xor(r1, 1));
        a1 = __fadd_rn(a1, __shfl_xor(a1, 2));
        a1 = __fadd_rn(a1, __shfl_xor(a1, 4));
        float a2 = __fadd_rn(r2, __shfl_xor(r2, 1));
        a2 = __fadd_rn(a2, __shfl_xor(a2, 2));
        a2 = __fadd_rn(a2, __shfl_xor(a2, 4));
        #pragma unroll
        for (int c = 0; c < 3; ++c) {
            float rc = (c == 0) ? a0 : ((c == 1) ? a1 : a2);
            __syncthreads();
            if (j == 0) lsum[t >> 3] = rc;
            __syncthreads();
            for (int m = 16; m >= 1; m >>= 1) {
                float v = 0.0f;
                if (t < m) v = __fadd_rn(lsum[2 * t], lsum[2 * t + 1]);
                __syncthreads();
                if (t < m) lsum[t] = v;
                __syncthreads();
            }
            if (t == 0) wsf[16 + ((size_t)(b * 3 + c) * 32 + s) * 8 + blk] = lsum[0];
        }
    }
}

// ---------------- K2: pw2 c-merged (rel3 stream, inline bit-exact mean3) ----
__global__ __launch_bounds__(256) void kpw2(const float3* __restrict__ rel3,
                                            float* __restrict__ wsf) {
    __shared__ float sm[96];
    int r8 = blockIdx.x;
    int s = r8 >> 3, blk = r8 & 7;
    int b = blockIdx.y;
    int t = threadIdx.x;

    if (t < 96) {
        int c = t >> 5, l = t & 31;
        const float* q = wsf + 16 + (size_t)(b * 3 + c) * 256 + l * 8;
        float a  = __fadd_rn(__fadd_rn(q[0], q[1]), __fadd_rn(q[2], q[3]));
        float b2 = __fadd_rn(__fadd_rn(q[4], q[5]), __fadd_rn(q[6], q[7]));
        sm[c * 32 + l] = __fadd_rn(a, b2);
    }
    __syncthreads();
    for (int m = 16; m >= 1; m >>= 1) {
        float v = 0.0f;
        int c = t >> 5, l = t & 31;
        if (t < 96 && l < m) v = __fadd_rn(sm[c * 32 + 2 * l], sm[c * 32 + 2 * l + 1]);
        __syncthreads();
        if (t < 96 && l < m) sm[c * 32 + l] = v;
        __syncthreads();
    }
    float m0 = sm[0]  / 800000.0f;
    float m1 = sm[32] / 800000.0f;
    float m2 = sm[64] / 800000.0f;
    __syncthreads();

    const float3* relb = rel3 + (size_t)b * MTOT;
    int l = blk * 32 + (t >> 3);
    int j = t & 7;
    int off, n;
    leafwalk(l, off, n);
    int base = s * 25000 + off;
    float r0 = 0.0f, r1 = 0.0f, r2 = 0.0f;
    int i = j;
    for (; i + 24 < n; i += 32) {
        float3 vA = relb[base + i];
        float3 vB = relb[base + i + 8];
        float3 vC = relb[base + i + 16];
        float3 vD = relb[base + i + 24];
        float dA0 = __fsub_rn(vA.x, m0), dA1 = __fsub_rn(vA.y, m1), dA2 = __fsub_rn(vA.z, m2);
        float dB0 = __fsub_rn(vB.x, m0), dB1 = __fsub_rn(vB.y, m1), dB2 = __fsub_rn(vB.z, m2);
        float dC0 = __fsub_rn(vC.x, m0), dC1 = __fsub_rn(vC.y, m1), dC2 = __fsub_rn(vC.z, m2);
        float dD0 = __fsub_rn(vD.x, m0), dD1 = __fsub_rn(vD.y, m1), dD2 = __fsub_rn(vD.z, m2);
        r0 = __fadd_rn(r0, __fmul_rn(dA0, dA0));
        r1 = __fadd_rn(r1, __fmul_rn(dA1, dA1));
        r2 = __fadd_rn(r2, __fmul_rn(dA2, dA2));
        r0 = __fadd_rn(r0, __fmul_rn(dB0, dB0));
        r1 = __fadd_rn(r1, __fmul_rn(dB1, dB1));
        r2 = __fadd_rn(r2, __fmul_rn(dB2, dB2));
        r0 = __fadd_rn(r0, __fmul_rn(dC0, dC0));
        r1 = __fadd_rn(r1, __fmul_rn(dC1, dC1));
        r2 = __fadd_rn(r2, __fmul_rn(dC2, dC2));
        r0 = __fadd_rn(r0, __fmul_rn(dD0, dD0));
        r1 = __fadd_rn(r1, __fmul_rn(dD1, dD1));
        r2 = __fadd_rn(r2, __fmul_rn(dD2, dD2));
    }
    for (; i < n; i += 8) {
        float3 v = relb[base + i];
        float d0 = __fsub_rn(v.x, m0), d1 = __fsub_rn(v.y, m1), d2 = __fsub_rn(v.z, m2);
        r0 = __fadd_rn(r0, __fmul_rn(d0, d0));
        r1 = __fadd_rn(r1, __fmul_rn(d1, d1));
        r2 = __fadd_rn(r2, __fmul_rn(d2, d2));
    }
    float a0 = __fadd_rn(r0, __shfl_xor(r0, 1));
    a0 = __fadd_rn(a0, __shfl_xor(a0, 2));
    a0 = __fadd_rn(a0, __shfl_xor(a0, 4));
    float a1 = __fadd_rn(r1, __shfl_xor(r1, 1));
    a1 = __fadd_rn(a1, __shfl_xor(a1, 2));
    a1 = __fadd_rn(a1, __shfl_xor(a1, 4));
    float a2 = __fadd_rn(r2, __shfl_xor(r2, 1));
    a2 = __fadd_rn(a2, __shfl_xor(a2, 2));
    a2 = __fadd_rn(a2, __shfl_xor(a2, 4));
    #pragma unroll
    for (int c = 0; c < 3; ++c) {
        float rc = (c == 0) ? a0 : ((c == 1) ? a1 : a2);
        __syncthreads();
        if (j == 0) sm[t >> 3] = rc;
        __syncthreads();
        for (int m = 16; m >= 1; m >>= 1) {
            float v = 0.0f;
            if (t < m) v = __fadd_rn(sm[2 * t], sm[2 * t + 1]);
            __syncthreads();
            if (t < m) sm[t] = v;
            __syncthreads();
        }
        if (t == 0) wsf[2048 + ((size_t)(b * 3 + c) * 32 + s) * 8 + blk] = sm[0];
    }
}

// ---------------- K3: kmain — 2-point staged gathers, XCD partition ---------
__global__ __launch_bounds__(256, 6) void kmain(const int* __restrict__ idx,
                                                const float* __restrict__ cb,
                                                const unsigned short* __restrict__ g,
                                                const float* __restrict__ wsf,
                                                float* __restrict__ out) {
    __shared__ unsigned int  dwp[NCELL * 32];    // 16000B
    __shared__ unsigned char celllds[64 * KNN];  // 1024B
    __shared__ float         ctr[3][64];         // 768B
    __shared__ float         res[128 * 17];      // 8704B  (l3 tree aliases res)
    int bx = blockIdx.x;
    // XCD-batch partition: XCD = bx%8; XCDs 0-3 -> b=0, 4-7 -> b=1
    int sub = bx & 7;
    int b = sub >> 2;
    int tile = (bx >> 3) * 4 + (sub & 3);
    if (tile >= 782) return;
    int n0 = tile * 64;
    int t = threadIdx.x;
    int nrem = NPTS - n0; if (nrem > 64) nrem = 64;

    float* l3 = res;
    if (t < 96) {
        int c = t >> 5, l = t & 31;
        const float* q = wsf + 2048 + (size_t)(b * 3 + c) * 256 + l * 8;
        float a  = __fadd_rn(__fadd_rn(q[0], q[1]), __fadd_rn(q[2], q[3]));
        float b2 = __fadd_rn(__fadd_rn(q[4], q[5]), __fadd_rn(q[6], q[7]));
        l3[c * 32 + l] = __fadd_rn(a, b2);
    }
    __syncthreads();
    for (int m = 16; m >= 1; m >>= 1) {
        float v = 0.0f;
        int c = t >> 5, l = t & 31;
        if (t < 96 && l < m) v = __fadd_rn(l3[c * 32 + 2 * l], l3[c * 32 + 2 * l + 1]);
        __syncthreads();
        if (t < 96 && l < m) l3[c * 32 + l] = v;
        __syncthreads();
    }
    float dn0 = __fmul_rn(4.0f, sqrtf(l3[0]  / 799999.0f));
    float dn1 = __fmul_rn(4.0f, sqrtf(l3[32] / 799999.0f));
    float dn2 = __fmul_rn(4.0f, sqrtf(l3[64] / 799999.0f));
    __syncthreads();

    const unsigned int* gdwp = (const unsigned int*)(wsf + 8192);
    for (int i = t; i < NCELL * 32; i += 256) dwp[i] = gdwp[i];
    const float3* xT = (const float3*)(wsf + 16384) + (size_t)b * NPTS;
    if (t < 64) {
        if (t < nrem) {
            float3 v = xT[n0 + t];
            ctr[0][t] = v.x; ctr[1][t] = v.y; ctr[2][t] = v.z;
        }
    }
    const int* ib = idx + ((size_t)b * NPTS + n0) * KNN;
    __syncthreads();

    for (int i = t; i < nrem * KNN; i += 256) {
        int p = i >> 4;
        int jx = ib[i];
        float3 pj = xT[jx];
        float sx = __fsub_rn(pj.x, ctr[0][p]) / dn0;
        float sy = __fsub_rn(pj.y, ctr[1][p]) / dn1;
        float sz = __fsub_rn(pj.z, ctr[2][p]) / dn2;
        celllds[i] = (unsigned char)((to_cell32(sz) * 5 + to_cell32(sy)) * 5 + to_cell32(sx));
    }
    __syncthreads();

    int w = t >> 6, h = (t >> 5) & 1, u = t & 31;
    int o0 = 2 * u, o1 = 2 * u + 1;
    f32x2 cbv;
    cbv.x = cb[o0]; cbv.y = cb[o1];
    const unsigned short* gbp = g + (size_t)b * NPTS * C2;
    float* ob = out + (size_t)b * 128 * NPTS;

    #pragma unroll 1
    for (int chunk = 0; chunk < 4; ++chunk) {
        int pbase = chunk * 16;
        int p0 = pbase + w * 2 + h;
        int p1 = pbase + 8 + w * 2 + h;
        bool v0 = p0 < nrem, v1 = p1 < nrem;
        // phase 1: issue gathers for BOTH points (up to 32 loads in flight)
        unsigned int gnu0 = 0, gnu1 = 0;
        unsigned int gvv0[15], gvv1[15];
        if (v0) {
            const int* row = ib + p0 * KNN;
            gnu0 = *(const unsigned int*)(gbp + (size_t)(n0 + p0) * C2 + o0);
            #pragma unroll
            for (int k = 0; k < 15; ++k)
                gvv0[k] = *(const unsigned int*)(gbp + (size_t)row[k + 1] * C2 + o0);
        }
        if (v1) {
            const int* row = ib + p1 * KNN;
            gnu1 = *(const unsigned int*)(gbp + (size_t)(n0 + p1) * C2 + o0);
            #pragma unroll
            for (int k = 0; k < 15; ++k)
                gvv1[k] = *(const unsigned int*)(gbp + (size_t)row[k + 1] * C2 + o0);
        }
        // phase 2: consume p0 then p1 (packed f32x2 math)
        if (v0) {
            int cell0 = celllds[p0 * KNN];
            f32x2 k0v = unpk(dwp[cell0 * 32 + u]);
            f32x2 gn  = unpk(gnu0);
            f32x2 ws = {0.f, 0.f}, gs = {0.f, 0.f}, sk = {0.f, 0.f};
            #pragma unroll
            for (int k = 0; k < 15; ++k) {
                int cell = celllds[p0 * KNN + k + 1];
                f32x2 dp = unpk(dwp[cell * 32 + u]);
                f32x2 gv = unpk(gvv0[k]);
                ws += dp * gv;
                gs += gv;
                sk += dp;
            }
            f32x2 r1 = cbv * (k0v + sk) + gn * (k0v - sk) + ws;
            f32x2 r2 = cbv + 0.0625f * (gs - 14.0f * gn);
            int pl = p0 & 15;
            res[o0 * 17 + pl]        = r1.x;
            res[o1 * 17 + pl]        = r1.y;
            res[(64 + o0) * 17 + pl] = r2.x;
            res[(64 + o1) * 17 + pl] = r2.y;
        }
        if (v1) {
            int cell0 = celllds[p1 * KNN];
            f32x2 k0v = unpk(dwp[cell0 * 32 + u]);
            f32x2 gn  = unpk(gnu1);
            f32x2 ws = {0.f, 0.f}, gs = {0.f, 0.f}, sk = {0.f, 0.f};
            #pragma unroll
            for (int k = 0; k < 15; ++k) {
                int cell = celllds[p1 * KNN + k + 1];
                f32x2 dp = unpk(dwp[cell * 32 + u]);
                f32x2 gv = unpk(gvv1[k]);
                ws += dp * gv;
                gs += gv;
                sk += dp;
            }
            f32x2 r1 = cbv * (k0v + sk) + gn * (k0v - sk) + ws;
            f32x2 r2 = cbv + 0.0625f * (gs - 14.0f * gn);
            int pl = p1 & 15;
            res[o0 * 17 + pl]        = r1.x;
            res[o1 * 17 + pl]        = r1.y;
            res[(64 + o0) * 17 + pl] = r2.x;
            res[(64 + o1) * 17 + pl] = r2.y;
        }
        __syncthreads();
        int rl = t >> 4;
        int jn = t & 15;
        int ncol = nrem - pbase; if (ncol > 16) ncol = 16;
        if (jn < ncol) {
            for (int r2 = rl; r2 < 128; r2 += 16)
                ob[(size_t)r2 * NPTS + n0 + pbase + jn] = res[r2 * 17 + jn];
        }
        __syncthreads();
    }
}

extern "C" void kernel_launch(void* const* d_in, const int* in_sizes, int n_in,
                              void* d_out, int out_size, void* d_ws, size_t ws_size,
                              hipStream_t stream) {
    const float* xyz   = (const float*)d_in[0];
    const float* fea   = (const float*)d_in[1];
    const int*   knn   = (const int*)d_in[2];
    const float* convw = (const float*)d_in[3];
    const float* convb = (const float*)d_in[4];
    const float* convdw= (const float*)d_in[5];
    float* out = (float*)d_out;
    float* wsf = (float*)d_ws;
    unsigned short* g = (unsigned short*)(wsf + 327680);
    float3* rel3 = (float3*)out;     // 19.2 MB scratch, fully overwritten by kmain

    kprep <<<407, 256, 0, stream>>>(xyz, convdw, wsf);
    kfuse1<<<1564 + 512, 256, 0, stream>>>(knn, fea, convw, g, rel3, wsf);
    kpw2  <<<dim3(256, BATCH), 256, 0, stream>>>(rel3, wsf);
    kmain <<<1568, 256, 0, stream>>>(knn, convb, g, wsf, out);
}

// Round 22
// 99.588 us; speedup vs baseline: 1.1618x; 1.1618x over previous
//
#include <hip/hip_runtime.h>
#include <hip/hip_bf16.h>
#include <math.h>

#define NPTS 50000
#define BATCH 2
#define CIN 64
#define C2 64
#define KNN 16
#define NCELL 125
#define MTOT 800000

// wsf layout (floats):
// [16..1552)    PART1: pass-1 partials (b*3+c)*256 + s*8 + blk
// [2048..3584)  PART2: pass-2 partials same indexing
// [8192..12192) packed dw table: 4000 uints
// [16384..316384)  xyzT[b*NPTS+n] float3 (1.2 MB)
// [327680..)    g[b][n][o] bf16 (12.8 MB)
// rel3 cache (19.2 MB, float3[b*MTOT+f]) lives in d_out (overwritten by kmain).

using bf16x8 = __attribute__((ext_vector_type(8))) short;
using f32x4  = __attribute__((ext_vector_type(4))) float;
using f32x2  = __attribute__((ext_vector_type(2))) float;

__device__ __forceinline__ f32x2 unpk(unsigned int v) {
    f32x2 r;
    r.x = __uint_as_float(v << 16);
    r.y = __uint_as_float(v & 0xffff0000u);
    return r;
}
__device__ __forceinline__ unsigned short f2bf(float f) {
    __hip_bfloat16 h = __float2bfloat16(f);
    return *(unsigned short*)&h;
}

__device__ __forceinline__ int to_cell32(float s) {
    float x = __fmul_rn(__fsub_rn(__fmul_rn(__fadd_rn(s, 1.0f), 5.0f), 1.0f), 0.5f);
    x = rintf(x);                       // half-to-even, matches np.round
    x = fminf(fmaxf(x, 0.0f), 4.0f);
    return (int)x;
}

// leaf bit-walk of numpy's pairwise split (n2 = n/2 - n/2%8), 8 levels, n=25000
__device__ __forceinline__ void leafwalk(int l, int& off, int& n) {
    off = 0; n = 25000;
    #pragma unroll
    for (int d = 7; d >= 0; --d) {
        int n2 = (n >> 1); n2 -= (n2 & 7);
        if ((l >> d) & 1) { off += n2; n -= n2; } else { n = n2; }
    }
}

// ---------------- K0: xyzT transpose (0..390) + dwpack (391..406) -----------
__global__ __launch_bounds__(256) void kprep(const float* __restrict__ xyz,
                                             const float* __restrict__ dw,
                                             float* __restrict__ wsf) {
    int bx = blockIdx.x;
    int t = threadIdx.x;
    if (bx < 391) {
        int gid = bx * 256 + t;
        if (gid < 2 * NPTS) {
            int b = (gid >= NPTS);
            int n = gid - b * NPTS;
            const float* xb = xyz + (size_t)b * 3 * NPTS;
            float3 v;
            v.x = xb[n]; v.y = xb[NPTS + n]; v.z = xb[2 * NPTS + n];
            ((float3*)(wsf + 16384))[gid] = v;
        }
    } else {
        unsigned int* gdwp = (unsigned int*)(wsf + 8192);
        int i0 = (bx - 391) * 250;
        for (int i = i0 + t; i < i0 + 250; i += 256) {
            int cell = i >> 5, u = i & 31;
            unsigned int p0 = f2bf(dw[(2 * u)     * NCELL + cell]);
            unsigned int p1 = f2bf(dw[(2 * u + 1) * NCELL + cell]);
            gdwp[i] = p0 | (p1 << 16);
        }
    }
}

// ---------------- K1: MFMA GEMM (0..1563, first) + pw1 tail (512) -----------
__global__ __launch_bounds__(256) void kfuse1(const int* __restrict__ knn,
                                              const float* __restrict__ fea,
                                              const float* __restrict__ W,
                                              unsigned short* __restrict__ g,
                                              float3* __restrict__ rel3,
                                              float* __restrict__ wsf) {
    __shared__ unsigned short flds[64 * 72];      // 9216B; pw1 aliases as lsum
    int bx = blockIdx.x;
    int t = threadIdx.x;
    if (bx < 1564) {
        // ---- MFMA GEMM: g[b][n][o] = sum_c W[o][c]*fea[b][c][n] -> bf16 ----
        int b = (bx >= 782);
        int tile = bx - b * 782;
        int n0 = tile * 64;
        int nrem = NPTS - n0; if (nrem > 64) nrem = 64;
        const float* fb = fea + (size_t)b * CIN * NPTS;
        int j = t & 63, w = t >> 6;
        int lane = t & 63, li = lane & 15, gq = lane >> 4;
        #pragma unroll
        for (int i = 0; i < 8; ++i) {
            int c = w * 2 + i * 8;
            float v0 = (j < nrem) ? fb[(size_t)c * NPTS + n0 + j] : 0.0f;
            float v1 = (j < nrem) ? fb[(size_t)(c + 1) * NPTS + n0 + j] : 0.0f;
            unsigned int pk = (unsigned int)f2bf(v0) | ((unsigned int)f2bf(v1) << 16);
            *(unsigned int*)&flds[j * 72 + c] = pk;
        }
        bf16x8 af[4][2];
        #pragma unroll
        for (int mt = 0; mt < 4; ++mt)
            #pragma unroll
            for (int kh = 0; kh < 2; ++kh) {
                const float* wp = W + (mt * 16 + li) * CIN + kh * 32 + gq * 8;
                float4 wa = *(const float4*)wp;
                float4 wb = *(const float4*)(wp + 4);
                bf16x8 a;
                a[0] = (short)f2bf(wa.x); a[1] = (short)f2bf(wa.y);
                a[2] = (short)f2bf(wa.z); a[3] = (short)f2bf(wa.w);
                a[4] = (short)f2bf(wb.x); a[5] = (short)f2bf(wb.y);
                a[6] = (short)f2bf(wb.z); a[7] = (short)f2bf(wb.w);
                af[mt][kh] = a;
            }
        __syncthreads();
        f32x4 acc[4];
        #pragma unroll
        for (int mt = 0; mt < 4; ++mt) acc[mt] = (f32x4){0.f, 0.f, 0.f, 0.f};
        #pragma unroll
        for (int kh = 0; kh < 2; ++kh) {
            bf16x8 bfv = *(const bf16x8*)&flds[(w * 16 + li) * 72 + kh * 32 + gq * 8];
            #pragma unroll
            for (int mt = 0; mt < 4; ++mt)
                acc[mt] = __builtin_amdgcn_mfma_f32_16x16x32_bf16(af[mt][kh], bfv,
                                                                  acc[mt], 0, 0, 0);
        }
        int nloc = w * 16 + li;
        if (nloc < nrem) {
            unsigned short* gr = g + ((size_t)b * NPTS + n0 + nloc) * C2;
            #pragma unroll
            for (int mt = 0; mt < 4; ++mt) {
                int ob = mt * 16 + gq * 4;
                uint2 pk;
                pk.x = (unsigned int)f2bf(acc[mt][0]) | ((unsigned int)f2bf(acc[mt][1]) << 16);
                pk.y = (unsigned int)f2bf(acc[mt][2]) | ((unsigned int)f2bf(acc[mt][3]) << 16);
                *(uint2*)(gr + ob) = pk;
            }
        }
    } else {
        // ---- pw1 tail (c-merged, unroll-4, xyzT float3 loads, rel3 store) --
        float* lsum = (float*)flds;
        const float3* xyzT = (const float3*)(wsf + 16384);
        int pid = bx - 1564;              // 0..511
        int b = pid >> 8, r8 = pid & 255;
        int s = r8 >> 3, blk = r8 & 7;
        const float3* xT = xyzT + (size_t)b * NPTS;
        const int* kb = knn + (size_t)b * NPTS * KNN;
        float3* relb = rel3 + (size_t)b * MTOT;
        int l = blk * 32 + (t >> 3);
        int j = t & 7;
        int off, n;
        leafwalk(l, off, n);
        int base = s * 25000 + off;
        float r0 = 0.0f, r1 = 0.0f, r2 = 0.0f;
        int i = j;
        for (; i + 24 < n; i += 32) {
            int f0 = base + i, f1 = f0 + 8, f2 = f0 + 16, f3 = f0 + 24;
            int kk0 = f0 / NPTS, nn0 = f0 - kk0 * NPTS;
            int kk1 = f1 / NPTS, nn1 = f1 - kk1 * NPTS;
            int kk2 = f2 / NPTS, nn2 = f2 - kk2 * NPTS;
            int kk3 = f3 / NPTS, nn3 = f3 - kk3 * NPTS;
            int jA = kb[nn0 * KNN + kk0];
            int jB = kb[nn1 * KNN + kk1];
            int jC = kb[nn2 * KNN + kk2];
            int jD = kb[nn3 * KNN + kk3];
            float3 cA = xT[nn0], nA = xT[jA];
            float3 cB = xT[nn1], nB = xT[jB];
            float3 cC = xT[nn2], nC = xT[jC];
            float3 cD = xT[nn3], nD = xT[jD];
            float3 vA, vB, vC, vD;
            vA.x = __fsub_rn(nA.x, cA.x); vA.y = __fsub_rn(nA.y, cA.y); vA.z = __fsub_rn(nA.z, cA.z);
            vB.x = __fsub_rn(nB.x, cB.x); vB.y = __fsub_rn(nB.y, cB.y); vB.z = __fsub_rn(nB.z, cB.z);
            vC.x = __fsub_rn(nC.x, cC.x); vC.y = __fsub_rn(nC.y, cC.y); vC.z = __fsub_rn(nC.z, cC.z);
            vD.x = __fsub_rn(nD.x, cD.x); vD.y = __fsub_rn(nD.y, cD.y); vD.z = __fsub_rn(nD.z, cD.z);
            relb[f0] = vA; relb[f1] = vB; relb[f2] = vC; relb[f3] = vD;
            // strict i-ascending accumulation per coord (bit-exact numpy chains)
            r0 = __fadd_rn(r0, vA.x); r1 = __fadd_rn(r1, vA.y); r2 = __fadd_rn(r2, vA.z);
            r0 = __fadd_rn(r0, vB.x); r1 = __fadd_rn(r1, vB.y); r2 = __fadd_rn(r2, vB.z);
            r0 = __fadd_rn(r0, vC.x); r1 = __fadd_rn(r1, vC.y); r2 = __fadd_rn(r2, vC.z);
            r0 = __fadd_rn(r0, vD.x); r1 = __fadd_rn(r1, vD.y); r2 = __fadd_rn(r2, vD.z);
        }
        for (; i < n; i += 8) {
            int f = base + i;
            int kk = f / NPTS, nn = f - kk * NPTS;
            int jj = kb[nn * KNN + kk];
            float3 cc = xT[nn], nv = xT[jj];
            float3 v;
            v.x = __fsub_rn(nv.x, cc.x); v.y = __fsub_rn(nv.y, cc.y); v.z = __fsub_rn(nv.z, cc.z);
            relb[f] = v;
            r0 = __fadd_rn(r0, v.x); r1 = __fadd_rn(r1, v.y); r2 = __fadd_rn(r2, v.z);
        }
        float a0 = __fadd_rn(r0, __shfl_xor(r0, 1));
        a0 = __fadd_rn(a0, __shfl_xor(a0, 2));
        a0 = __fadd_rn(a0, __shfl_xor(a0, 4));
        float a1 = __fadd_rn(r1, __shfl_xor(r1, 1));
        a1 = __fadd_rn(a1, __shfl_xor(a1, 2));
        a1 = __fadd_rn(a1, __shfl_xor(a1, 4));
        float a2 = __fadd_rn(r2, __shfl_xor(r2, 1));
        a2 = __fadd_rn(a2, __shfl_xor(a2, 2));
        a2 = __fadd_rn(a2, __shfl_xor(a2, 4));
        #pragma unroll
        for (int c = 0; c < 3; ++c) {
            float rc = (c == 0) ? a0 : ((c == 1) ? a1 : a2);
            __syncthreads();
            if (j == 0) lsum[t >> 3] = rc;
            __syncthreads();
            for (int m = 16; m >= 1; m >>= 1) {
                float v = 0.0f;
                if (t < m) v = __fadd_rn(lsum[2 * t], lsum[2 * t + 1]);
                __syncthreads();
                if (t < m) lsum[t] = v;
                __syncthreads();
            }
            if (t == 0) wsf[16 + ((size_t)(b * 3 + c) * 32 + s) * 8 + blk] = lsum[0];
        }
    }
}

// ---------------- K2: pw2 c-merged (rel3 stream, inline bit-exact mean3) ----
__global__ __launch_bounds__(256) void kpw2(const float3* __restrict__ rel3,
                                            float* __restrict__ wsf) {
    __shared__ float sm[96];
    int r8 = blockIdx.x;
    int s = r8 >> 3, blk = r8 & 7;
    int b = blockIdx.y;
    int t = threadIdx.x;

    if (t < 96) {
        int c = t >> 5, l = t & 31;
        const float* q = wsf + 16 + (size_t)(b * 3 + c) * 256 + l * 8;
        float a  = __fadd_rn(__fadd_rn(q[0], q[1]), __fadd_rn(q[2], q[3]));
        float b2 = __fadd_rn(__fadd_rn(q[4], q[5]), __fadd_rn(q[6], q[7]));
        sm[c * 32 + l] = __fadd_rn(a, b2);
    }
    __syncthreads();
    for (int m = 16; m >= 1; m >>= 1) {
        float v = 0.0f;
        int c = t >> 5, l = t & 31;
        if (t < 96 && l < m) v = __fadd_rn(sm[c * 32 + 2 * l], sm[c * 32 + 2 * l + 1]);
        __syncthreads();
        if (t < 96 && l < m) sm[c * 32 + l] = v;
        __syncthreads();
    }
    float m0 = sm[0]  / 800000.0f;
    float m1 = sm[32] / 800000.0f;
    float m2 = sm[64] / 800000.0f;
    __syncthreads();

    const float3* relb = rel3 + (size_t)b * MTOT;
    int l = blk * 32 + (t >> 3);
    int j = t & 7;
    int off, n;
    leafwalk(l, off, n);
    int base = s * 25000 + off;
    float r0 = 0.0f, r1 = 0.0f, r2 = 0.0f;
    int i = j;
    for (; i + 24 < n; i += 32) {
        float3 vA = relb[base + i];
        float3 vB = relb[base + i + 8];
        float3 vC = relb[base + i + 16];
        float3 vD = relb[base + i + 24];
        float dA0 = __fsub_rn(vA.x, m0), dA1 = __fsub_rn(vA.y, m1), dA2 = __fsub_rn(vA.z, m2);
        float dB0 = __fsub_rn(vB.x, m0), dB1 = __fsub_rn(vB.y, m1), dB2 = __fsub_rn(vB.z, m2);
        float dC0 = __fsub_rn(vC.x, m0), dC1 = __fsub_rn(vC.y, m1), dC2 = __fsub_rn(vC.z, m2);
        float dD0 = __fsub_rn(vD.x, m0), dD1 = __fsub_rn(vD.y, m1), dD2 = __fsub_rn(vD.z, m2);
        r0 = __fadd_rn(r0, __fmul_rn(dA0, dA0));
        r1 = __fadd_rn(r1, __fmul_rn(dA1, dA1));
        r2 = __fadd_rn(r2, __fmul_rn(dA2, dA2));
        r0 = __fadd_rn(r0, __fmul_rn(dB0, dB0));
        r1 = __fadd_rn(r1, __fmul_rn(dB1, dB1));
        r2 = __fadd_rn(r2, __fmul_rn(dB2, dB2));
        r0 = __fadd_rn(r0, __fmul_rn(dC0, dC0));
        r1 = __fadd_rn(r1, __fmul_rn(dC1, dC1));
        r2 = __fadd_rn(r2, __fmul_rn(dC2, dC2));
        r0 = __fadd_rn(r0, __fmul_rn(dD0, dD0));
        r1 = __fadd_rn(r1, __fmul_rn(dD1, dD1));
        r2 = __fadd_rn(r2, __fmul_rn(dD2, dD2));
    }
    for (; i < n; i += 8) {
        float3 v = relb[base + i];
        float d0 = __fsub_rn(v.x, m0), d1 = __fsub_rn(v.y, m1), d2 = __fsub_rn(v.z, m2);
        r0 = __fadd_rn(r0, __fmul_rn(d0, d0));
        r1 = __fadd_rn(r1, __fmul_rn(d1, d1));
        r2 = __fadd_rn(r2, __fmul_rn(d2, d2));
    }
    float a0 = __fadd_rn(r0, __shfl_xor(r0, 1));
    a0 = __fadd_rn(a0, __shfl_xor(a0, 2));
    a0 = __fadd_rn(a0, __shfl_xor(a0, 4));
    float a1 = __fadd_rn(r1, __shfl_xor(r1, 1));
    a1 = __fadd_rn(a1, __shfl_xor(a1, 2));
    a1 = __fadd_rn(a1, __shfl_xor(a1, 4));
    float a2 = __fadd_rn(r2, __shfl_xor(r2, 1));
    a2 = __fadd_rn(a2, __shfl_xor(a2, 2));
    a2 = __fadd_rn(a2, __shfl_xor(a2, 4));
    #pragma unroll
    for (int c = 0; c < 3; ++c) {
        float rc = (c == 0) ? a0 : ((c == 1) ? a1 : a2);
        __syncthreads();
        if (j == 0) sm[t >> 3] = rc;
        __syncthreads();
        for (int m = 16; m >= 1; m >>= 1) {
            float v = 0.0f;
            if (t < m) v = __fadd_rn(sm[2 * t], sm[2 * t + 1]);
            __syncthreads();
            if (t < m) sm[t] = v;
            __syncthreads();
        }
        if (t == 0) wsf[2048 + ((size_t)(b * 3 + c) * 32 + s) * 8 + blk] = sm[0];
    }
}

// ---------------- K3: kmain — XCD-batch partition, staged gathers, f32x2 ----
__global__ __launch_bounds__(256, 6) void kmain(const int* __restrict__ idx,
                                                const float* __restrict__ cb,
                                                const unsigned short* __restrict__ g,
                                                const float* __restrict__ wsf,
                                                float* __restrict__ out) {
    __shared__ unsigned int  dwp[NCELL * 32];    // 16000B
    __shared__ unsigned char celllds[64 * KNN];  // 1024B
    __shared__ float         ctr[3][64];         // 768B
    __shared__ float         res[128 * 17];      // 8704B  (l3 tree aliases res)
    int bx = blockIdx.x;
    // XCD-batch partition: XCD = bx%8; XCDs 0-3 -> b=0, 4-7 -> b=1
    int sub = bx & 7;
    int b = sub >> 2;
    int tile = (bx >> 3) * 4 + (sub & 3);
    if (tile >= 782) return;
    int n0 = tile * 64;
    int t = threadIdx.x;
    int nrem = NPTS - n0; if (nrem > 64) nrem = 64;

    float* l3 = res;
    if (t < 96) {
        int c = t >> 5, l = t & 31;
        const float* q = wsf + 2048 + (size_t)(b * 3 + c) * 256 + l * 8;
        float a  = __fadd_rn(__fadd_rn(q[0], q[1]), __fadd_rn(q[2], q[3]));
        float b2 = __fadd_rn(__fadd_rn(q[4], q[5]), __fadd_rn(q[6], q[7]));
        l3[c * 32 + l] = __fadd_rn(a, b2);
    }
    __syncthreads();
    for (int m = 16; m >= 1; m >>= 1) {
        float v = 0.0f;
        int c = t >> 5, l = t & 31;
        if (t < 96 && l < m) v = __fadd_rn(l3[c * 32 + 2 * l], l3[c * 32 + 2 * l + 1]);
        __syncthreads();
        if (t < 96 && l < m) l3[c * 32 + l] = v;
        __syncthreads();
    }
    float dn0 = __fmul_rn(4.0f, sqrtf(l3[0]  / 799999.0f));
    float dn1 = __fmul_rn(4.0f, sqrtf(l3[32] / 799999.0f));
    float dn2 = __fmul_rn(4.0f, sqrtf(l3[64] / 799999.0f));
    __syncthreads();

    const unsigned int* gdwp = (const unsigned int*)(wsf + 8192);
    for (int i = t; i < NCELL * 32; i += 256) dwp[i] = gdwp[i];
    const float3* xT = (const float3*)(wsf + 16384) + (size_t)b * NPTS;
    if (t < 64) {
        if (t < nrem) {
            float3 v = xT[n0 + t];
            ctr[0][t] = v.x; ctr[1][t] = v.y; ctr[2][t] = v.z;
        }
    }
    const int* ib = idx + ((size_t)b * NPTS + n0) * KNN;
    __syncthreads();

    for (int i = t; i < nrem * KNN; i += 256) {
        int p = i >> 4;
        int jx = ib[i];
        float3 pj = xT[jx];
        float sx = __fsub_rn(pj.x, ctr[0][p]) / dn0;
        float sy = __fsub_rn(pj.y, ctr[1][p]) / dn1;
        float sz = __fsub_rn(pj.z, ctr[2][p]) / dn2;
        celllds[i] = (unsigned char)((to_cell32(sz) * 5 + to_cell32(sy)) * 5 + to_cell32(sx));
    }
    __syncthreads();

    int w = t >> 6, h = (t >> 5) & 1, u = t & 31;
    int o0 = 2 * u, o1 = 2 * u + 1;
    f32x2 cbv;
    cbv.x = cb[o0]; cbv.y = cb[o1];
    const unsigned short* gbp = g + (size_t)b * NPTS * C2;
    float* ob = out + (size_t)b * 128 * NPTS;

    #pragma unroll 1
    for (int chunk = 0; chunk < 4; ++chunk) {
        int pbase = chunk * 16;
        #pragma unroll 1
        for (int i = 0; i < 2; ++i) {
            int p = pbase + i * 8 + w * 2 + h;
            if (p < nrem) {
                const int* row = ib + p * KNN;
                unsigned int gnu = *(const unsigned int*)(gbp + (size_t)(n0 + p) * C2 + o0);
                unsigned int gvv[15];
                #pragma unroll
                for (int k = 0; k < 15; ++k) {
                    int jj = row[k + 1];
                    gvv[k] = *(const unsigned int*)(gbp + (size_t)jj * C2 + o0);
                }
                int cell0 = celllds[p * KNN];
                f32x2 k0v = unpk(dwp[cell0 * 32 + u]);
                f32x2 gn  = unpk(gnu);
                f32x2 ws = {0.f, 0.f}, gs = {0.f, 0.f}, sk = {0.f, 0.f};
                #pragma unroll
                for (int k = 0; k < 15; ++k) {
                    int cell = celllds[p * KNN + k + 1];
                    f32x2 dp = unpk(dwp[cell * 32 + u]);
                    f32x2 gv = unpk(gvv[k]);
                    ws += dp * gv;
                    gs += gv;
                    sk += dp;
                }
                f32x2 r1 = cbv * (k0v + sk) + gn * (k0v - sk) + ws;
                f32x2 r2 = cbv + 0.0625f * (gs - 14.0f * gn);
                int pl = p & 15;
                res[o0 * 17 + pl]        = r1.x;
                res[o1 * 17 + pl]        = r1.y;
                res[(64 + o0) * 17 + pl] = r2.x;
                res[(64 + o1) * 17 + pl] = r2.y;
            }
        }
        __syncthreads();
        int rl = t >> 4;
        int jn = t & 15;
        int ncol = nrem - pbase; if (ncol > 16) ncol = 16;
        if (jn < ncol) {
            for (int r2 = rl; r2 < 128; r2 += 16)
                ob[(size_t)r2 * NPTS + n0 + pbase + jn] = res[r2 * 17 + jn];
        }
        __syncthreads();
    }
}

extern "C" void kernel_launch(void* const* d_in, const int* in_sizes, int n_in,
                              void* d_out, int out_size, void* d_ws, size_t ws_size,
                              hipStream_t stream) {
    const float* xyz   = (const float*)d_in[0];
    const float* fea   = (const float*)d_in[1];
    const int*   knn   = (const int*)d_in[2];
    const float* convw = (const float*)d_in[3];
    const float* convb = (const float*)d_in[4];
    const float* convdw= (const float*)d_in[5];
    float* out = (float*)d_out;
    float* wsf = (float*)d_ws;
    unsigned short* g = (unsigned short*)(wsf + 327680);
    float3* rel3 = (float3*)out;     // 19.2 MB scratch, fully overwritten by kmain

    kprep <<<407, 256, 0, stream>>>(xyz, convdw, wsf);
    kfuse1<<<1564 + 512, 256, 0, stream>>>(knn, fea, convw, g, rel3, wsf);
    kpw2  <<<dim3(256, BATCH), 256, 0, stream>>>(rel3, wsf);
    kmain <<<1568, 256, 0, stream>>>(knn, convb, g, wsf, out);
}

// Round 23
// 96.267 us; speedup vs baseline: 1.2019x; 1.0345x over previous
//
#include <hip/hip_runtime.h>
#include <hip/hip_bf16.h>
#include <math.h>

#define NPTS 50000
#define BATCH 2
#define CIN 64
#define C2 64
#define KNN 16
#define NCELL 125
#define MTOT 800000

// wsf layout (floats):
// [16..1552)    PART1: pass-1 partials (b*3+c)*256 + s*8 + blk
// [2048..3584)  PART2: pass-2 partials same indexing
// [8192..12192) packed dw table: 4000 uints
// [16384..316384)  xyzT[b*NPTS+n] float3 (1.2 MB)
// [327680..)    g[b][n][o] bf16 (12.8 MB)
// rel3 cache (19.2 MB, float3[b*MTOT+f]) lives in d_out (overwritten by kmain).

using bf16x8 = __attribute__((ext_vector_type(8))) short;
using f32x4  = __attribute__((ext_vector_type(4))) float;
using f32x2  = __attribute__((ext_vector_type(2))) float;

__device__ __forceinline__ f32x2 unpk(unsigned int v) {
    f32x2 r;
    r.x = __uint_as_float(v << 16);
    r.y = __uint_as_float(v & 0xffff0000u);
    return r;
}
__device__ __forceinline__ unsigned short f2bf(float f) {
    __hip_bfloat16 h = __float2bfloat16(f);
    return *(unsigned short*)&h;
}

__device__ __forceinline__ int to_cell32(float s) {
    float x = __fmul_rn(__fsub_rn(__fmul_rn(__fadd_rn(s, 1.0f), 5.0f), 1.0f), 0.5f);
    x = rintf(x);                       // half-to-even, matches np.round
    x = fminf(fmaxf(x, 0.0f), 4.0f);
    return (int)x;
}

// leaf bit-walk of numpy's pairwise split (n2 = n/2 - n/2%8), 8 levels, n=25000
__device__ __forceinline__ void leafwalk(int l, int& off, int& n) {
    off = 0; n = 25000;
    #pragma unroll
    for (int d = 7; d >= 0; --d) {
        int n2 = (n >> 1); n2 -= (n2 & 7);
        if ((l >> d) & 1) { off += n2; n -= n2; } else { n = n2; }
    }
}

// ---------------- K0: xyzT transpose (0..390) + dwpack (391..406) -----------
__global__ __launch_bounds__(256) void kprep(const float* __restrict__ xyz,
                                             const float* __restrict__ dw,
                                             float* __restrict__ wsf) {
    int bx = blockIdx.x;
    int t = threadIdx.x;
    if (bx < 391) {
        int gid = bx * 256 + t;
        if (gid < 2 * NPTS) {
            int b = (gid >= NPTS);
            int n = gid - b * NPTS;
            const float* xb = xyz + (size_t)b * 3 * NPTS;
            float3 v;
            v.x = xb[n]; v.y = xb[NPTS + n]; v.z = xb[2 * NPTS + n];
            ((float3*)(wsf + 16384))[gid] = v;
        }
    } else {
        unsigned int* gdwp = (unsigned int*)(wsf + 8192);
        int i0 = (bx - 391) * 250;
        for (int i = i0 + t; i < i0 + 250; i += 256) {
            int cell = i >> 5, u = i & 31;
            unsigned int p0 = f2bf(dw[(2 * u)     * NCELL + cell]);
            unsigned int p1 = f2bf(dw[(2 * u + 1) * NCELL + cell]);
            gdwp[i] = p0 | (p1 << 16);
        }
    }
}

// ---------------- K1: MFMA GEMM (0..1563, first) + pw1 tail (512) -----------
__global__ __launch_bounds__(256) void kfuse1(const int* __restrict__ knn,
                                              const float* __restrict__ fea,
                                              const float* __restrict__ W,
                                              unsigned short* __restrict__ g,
                                              float3* __restrict__ rel3,
                                              float* __restrict__ wsf) {
    __shared__ unsigned short flds[64 * 72];      // 9216B; pw1 aliases as lsum
    int bx = blockIdx.x;
    int t = threadIdx.x;
    if (bx < 1564) {
        // ---- MFMA GEMM: g[b][n][o] = sum_c W[o][c]*fea[b][c][n] -> bf16 ----
        int b = (bx >= 782);
        int tile = bx - b * 782;
        int n0 = tile * 64;
        int nrem = NPTS - n0; if (nrem > 64) nrem = 64;
        const float* fb = fea + (size_t)b * CIN * NPTS;
        int j = t & 63, w = t >> 6;
        int lane = t & 63, li = lane & 15, gq = lane >> 4;
        #pragma unroll
        for (int i = 0; i < 8; ++i) {
            int c = w * 2 + i * 8;
            float v0 = (j < nrem) ? fb[(size_t)c * NPTS + n0 + j] : 0.0f;
            float v1 = (j < nrem) ? fb[(size_t)(c + 1) * NPTS + n0 + j] : 0.0f;
            unsigned int pk = (unsigned int)f2bf(v0) | ((unsigned int)f2bf(v1) << 16);
            *(unsigned int*)&flds[j * 72 + c] = pk;
        }
        bf16x8 af[4][2];
        #pragma unroll
        for (int mt = 0; mt < 4; ++mt)
            #pragma unroll
            for (int kh = 0; kh < 2; ++kh) {
                const float* wp = W + (mt * 16 + li) * CIN + kh * 32 + gq * 8;
                float4 wa = *(const float4*)wp;
                float4 wb = *(const float4*)(wp + 4);
                bf16x8 a;
                a[0] = (short)f2bf(wa.x); a[1] = (short)f2bf(wa.y);
                a[2] = (short)f2bf(wa.z); a[3] = (short)f2bf(wa.w);
                a[4] = (short)f2bf(wb.x); a[5] = (short)f2bf(wb.y);
                a[6] = (short)f2bf(wb.z); a[7] = (short)f2bf(wb.w);
                af[mt][kh] = a;
            }
        __syncthreads();
        f32x4 acc[4];
        #pragma unroll
        for (int mt = 0; mt < 4; ++mt) acc[mt] = (f32x4){0.f, 0.f, 0.f, 0.f};
        #pragma unroll
        for (int kh = 0; kh < 2; ++kh) {
            bf16x8 bfv = *(const bf16x8*)&flds[(w * 16 + li) * 72 + kh * 32 + gq * 8];
            #pragma unroll
            for (int mt = 0; mt < 4; ++mt)
                acc[mt] = __builtin_amdgcn_mfma_f32_16x16x32_bf16(af[mt][kh], bfv,
                                                                  acc[mt], 0, 0, 0);
        }
        int nloc = w * 16 + li;
        if (nloc < nrem) {
            unsigned short* gr = g + ((size_t)b * NPTS + n0 + nloc) * C2;
            #pragma unroll
            for (int mt = 0; mt < 4; ++mt) {
                int ob = mt * 16 + gq * 4;
                uint2 pk;
                pk.x = (unsigned int)f2bf(acc[mt][0]) | ((unsigned int)f2bf(acc[mt][1]) << 16);
                pk.y = (unsigned int)f2bf(acc[mt][2]) | ((unsigned int)f2bf(acc[mt][3]) << 16);
                *(uint2*)(gr + ob) = pk;
            }
        }
    } else {
        // ---- pw1 tail (c-merged, unroll-4, xyzT float3 loads, rel3 store) --
        float* lsum = (float*)flds;
        const float3* xyzT = (const float3*)(wsf + 16384);
        int pid = bx - 1564;              // 0..511
        int b = pid >> 8, r8 = pid & 255;
        int s = r8 >> 3, blk = r8 & 7;
        const float3* xT = xyzT + (size_t)b * NPTS;
        const int* kb = knn + (size_t)b * NPTS * KNN;
        float3* relb = rel3 + (size_t)b * MTOT;
        int l = blk * 32 + (t >> 3);
        int j = t & 7;
        int off, n;
        leafwalk(l, off, n);
        int base = s * 25000 + off;
        float r0 = 0.0f, r1 = 0.0f, r2 = 0.0f;
        int i = j;
        for (; i + 24 < n; i += 32) {
            int f0 = base + i, f1 = f0 + 8, f2 = f0 + 16, f3 = f0 + 24;
            int kk0 = f0 / NPTS, nn0 = f0 - kk0 * NPTS;
            int kk1 = f1 / NPTS, nn1 = f1 - kk1 * NPTS;
            int kk2 = f2 / NPTS, nn2 = f2 - kk2 * NPTS;
            int kk3 = f3 / NPTS, nn3 = f3 - kk3 * NPTS;
            int jA = kb[nn0 * KNN + kk0];
            int jB = kb[nn1 * KNN + kk1];
            int jC = kb[nn2 * KNN + kk2];
            int jD = kb[nn3 * KNN + kk3];
            float3 cA = xT[nn0], nA = xT[jA];
            float3 cB = xT[nn1], nB = xT[jB];
            float3 cC = xT[nn2], nC = xT[jC];
            float3 cD = xT[nn3], nD = xT[jD];
            float3 vA, vB, vC, vD;
            vA.x = __fsub_rn(nA.x, cA.x); vA.y = __fsub_rn(nA.y, cA.y); vA.z = __fsub_rn(nA.z, cA.z);
            vB.x = __fsub_rn(nB.x, cB.x); vB.y = __fsub_rn(nB.y, cB.y); vB.z = __fsub_rn(nB.z, cB.z);
            vC.x = __fsub_rn(nC.x, cC.x); vC.y = __fsub_rn(nC.y, cC.y); vC.z = __fsub_rn(nC.z, cC.z);
            vD.x = __fsub_rn(nD.x, cD.x); vD.y = __fsub_rn(nD.y, cD.y); vD.z = __fsub_rn(nD.z, cD.z);
            relb[f0] = vA; relb[f1] = vB; relb[f2] = vC; relb[f3] = vD;
            // strict i-ascending accumulation per coord (bit-exact numpy chains)
            r0 = __fadd_rn(r0, vA.x); r1 = __fadd_rn(r1, vA.y); r2 = __fadd_rn(r2, vA.z);
            r0 = __fadd_rn(r0, vB.x); r1 = __fadd_rn(r1, vB.y); r2 = __fadd_rn(r2, vB.z);
            r0 = __fadd_rn(r0, vC.x); r1 = __fadd_rn(r1, vC.y); r2 = __fadd_rn(r2, vC.z);
            r0 = __fadd_rn(r0, vD.x); r1 = __fadd_rn(r1, vD.y); r2 = __fadd_rn(r2, vD.z);
        }
        for (; i < n; i += 8) {
            int f = base + i;
            int kk = f / NPTS, nn = f - kk * NPTS;
            int jj = kb[nn * KNN + kk];
            float3 cc = xT[nn], nv = xT[jj];
            float3 v;
            v.x = __fsub_rn(nv.x, cc.x); v.y = __fsub_rn(nv.y, cc.y); v.z = __fsub_rn(nv.z, cc.z);
            relb[f] = v;
            r0 = __fadd_rn(r0, v.x); r1 = __fadd_rn(r1, v.y); r2 = __fadd_rn(r2, v.z);
        }
        float a0 = __fadd_rn(r0, __shfl_xor(r0, 1));
        a0 = __fadd_rn(a0, __shfl_xor(a0, 2));
        a0 = __fadd_rn(a0, __shfl_xor(a0, 4));
        float a1 = __fadd_rn(r1, __shfl_xor(r1, 1));
        a1 = __fadd_rn(a1, __shfl_xor(a1, 2));
        a1 = __fadd_rn(a1, __shfl_xor(a1, 4));
        float a2 = __fadd_rn(r2, __shfl_xor(r2, 1));
        a2 = __fadd_rn(a2, __shfl_xor(a2, 2));
        a2 = __fadd_rn(a2, __shfl_xor(a2, 4));
        #pragma unroll
        for (int c = 0; c < 3; ++c) {
            float rc = (c == 0) ? a0 : ((c == 1) ? a1 : a2);
            __syncthreads();
            if (j == 0) lsum[t >> 3] = rc;
            __syncthreads();
            for (int m = 16; m >= 1; m >>= 1) {
                float v = 0.0f;
                if (t < m) v = __fadd_rn(lsum[2 * t], lsum[2 * t + 1]);
                __syncthreads();
                if (t < m) lsum[t] = v;
                __syncthreads();
            }
            if (t == 0) wsf[16 + ((size_t)(b * 3 + c) * 32 + s) * 8 + blk] = lsum[0];
        }
    }
}

// ---------------- K2: pw2 c-merged (rel3 stream, inline bit-exact mean3) ----
__global__ __launch_bounds__(256) void kpw2(const float3* __restrict__ rel3,
                                            float* __restrict__ wsf) {
    __shared__ float sm[96];
    int r8 = blockIdx.x;
    int s = r8 >> 3, blk = r8 & 7;
    int b = blockIdx.y;
    int t = threadIdx.x;

    if (t < 96) {
        int c = t >> 5, l = t & 31;
        const float* q = wsf + 16 + (size_t)(b * 3 + c) * 256 + l * 8;
        float a  = __fadd_rn(__fadd_rn(q[0], q[1]), __fadd_rn(q[2], q[3]));
        float b2 = __fadd_rn(__fadd_rn(q[4], q[5]), __fadd_rn(q[6], q[7]));
        sm[c * 32 + l] = __fadd_rn(a, b2);
    }
    __syncthreads();
    for (int m = 16; m >= 1; m >>= 1) {
        float v = 0.0f;
        int c = t >> 5, l = t & 31;
        if (t < 96 && l < m) v = __fadd_rn(sm[c * 32 + 2 * l], sm[c * 32 + 2 * l + 1]);
        __syncthreads();
        if (t < 96 && l < m) sm[c * 32 + l] = v;
        __syncthreads();
    }
    float m0 = sm[0]  / 800000.0f;
    float m1 = sm[32] / 800000.0f;
    float m2 = sm[64] / 800000.0f;
    __syncthreads();

    const float3* relb = rel3 + (size_t)b * MTOT;
    int l = blk * 32 + (t >> 3);
    int j = t & 7;
    int off, n;
    leafwalk(l, off, n);
    int base = s * 25000 + off;
    float r0 = 0.0f, r1 = 0.0f, r2 = 0.0f;
    int i = j;
    for (; i + 24 < n; i += 32) {
        float3 vA = relb[base + i];
        float3 vB = relb[base + i + 8];
        float3 vC = relb[base + i + 16];
        float3 vD = relb[base + i + 24];
        float dA0 = __fsub_rn(vA.x, m0), dA1 = __fsub_rn(vA.y, m1), dA2 = __fsub_rn(vA.z, m2);
        float dB0 = __fsub_rn(vB.x, m0), dB1 = __fsub_rn(vB.y, m1), dB2 = __fsub_rn(vB.z, m2);
        float dC0 = __fsub_rn(vC.x, m0), dC1 = __fsub_rn(vC.y, m1), dC2 = __fsub_rn(vC.z, m2);
        float dD0 = __fsub_rn(vD.x, m0), dD1 = __fsub_rn(vD.y, m1), dD2 = __fsub_rn(vD.z, m2);
        r0 = __fadd_rn(r0, __fmul_rn(dA0, dA0));
        r1 = __fadd_rn(r1, __fmul_rn(dA1, dA1));
        r2 = __fadd_rn(r2, __fmul_rn(dA2, dA2));
        r0 = __fadd_rn(r0, __fmul_rn(dB0, dB0));
        r1 = __fadd_rn(r1, __fmul_rn(dB1, dB1));
        r2 = __fadd_rn(r2, __fmul_rn(dB2, dB2));
        r0 = __fadd_rn(r0, __fmul_rn(dC0, dC0));
        r1 = __fadd_rn(r1, __fmul_rn(dC1, dC1));
        r2 = __fadd_rn(r2, __fmul_rn(dC2, dC2));
        r0 = __fadd_rn(r0, __fmul_rn(dD0, dD0));
        r1 = __fadd_rn(r1, __fmul_rn(dD1, dD1));
        r2 = __fadd_rn(r2, __fmul_rn(dD2, dD2));
    }
    for (; i < n; i += 8) {
        float3 v = relb[base + i];
        float d0 = __fsub_rn(v.x, m0), d1 = __fsub_rn(v.y, m1), d2 = __fsub_rn(v.z, m2);
        r0 = __fadd_rn(r0, __fmul_rn(d0, d0));
        r1 = __fadd_rn(r1, __fmul_rn(d1, d1));
        r2 = __fadd_rn(r2, __fmul_rn(d2, d2));
    }
    float a0 = __fadd_rn(r0, __shfl_xor(r0, 1));
    a0 = __fadd_rn(a0, __shfl_xor(a0, 2));
    a0 = __fadd_rn(a0, __shfl_xor(a0, 4));
    float a1 = __fadd_rn(r1, __shfl_xor(r1, 1));
    a1 = __fadd_rn(a1, __shfl_xor(a1, 2));
    a1 = __fadd_rn(a1, __shfl_xor(a1, 4));
    float a2 = __fadd_rn(r2, __shfl_xor(r2, 1));
    a2 = __fadd_rn(a2, __shfl_xor(a2, 2));
    a2 = __fadd_rn(a2, __shfl_xor(a2, 4));
    #pragma unroll
    for (int c = 0; c < 3; ++c) {
        float rc = (c == 0) ? a0 : ((c == 1) ? a1 : a2);
        __syncthreads();
        if (j == 0) sm[t >> 3] = rc;
        __syncthreads();
        for (int m = 16; m >= 1; m >>= 1) {
            float v = 0.0f;
            if (t < m) v = __fadd_rn(sm[2 * t], sm[2 * t + 1]);
            __syncthreads();
            if (t < m) sm[t] = v;
            __syncthreads();
        }
        if (t == 0) wsf[2048 + ((size_t)(b * 3 + c) * 32 + s) * 8 + blk] = sm[0];
    }
}

// ---------------- K3: kmain — XCD partition, staged gathers, nt out-stores --
__global__ __launch_bounds__(256, 6) void kmain(const int* __restrict__ idx,
                                                const float* __restrict__ cb,
                                                const unsigned short* __restrict__ g,
                                                const float* __restrict__ wsf,
                                                float* __restrict__ out) {
    __shared__ unsigned int  dwp[NCELL * 32];    // 16000B
    __shared__ unsigned char celllds[64 * KNN];  // 1024B
    __shared__ float         ctr[3][64];         // 768B
    __shared__ float         res[128 * 17];      // 8704B  (l3 tree aliases res)
    int bx = blockIdx.x;
    // XCD-batch partition: XCD = bx%8; XCDs 0-3 -> b=0, 4-7 -> b=1
    int sub = bx & 7;
    int b = sub >> 2;
    int tile = (bx >> 3) * 4 + (sub & 3);
    if (tile >= 782) return;
    int n0 = tile * 64;
    int t = threadIdx.x;
    int nrem = NPTS - n0; if (nrem > 64) nrem = 64;

    float* l3 = res;
    if (t < 96) {
        int c = t >> 5, l = t & 31;
        const float* q = wsf + 2048 + (size_t)(b * 3 + c) * 256 + l * 8;
        float a  = __fadd_rn(__fadd_rn(q[0], q[1]), __fadd_rn(q[2], q[3]));
        float b2 = __fadd_rn(__fadd_rn(q[4], q[5]), __fadd_rn(q[6], q[7]));
        l3[c * 32 + l] = __fadd_rn(a, b2);
    }
    __syncthreads();
    for (int m = 16; m >= 1; m >>= 1) {
        float v = 0.0f;
        int c = t >> 5, l = t & 31;
        if (t < 96 && l < m) v = __fadd_rn(l3[c * 32 + 2 * l], l3[c * 32 + 2 * l + 1]);
        __syncthreads();
        if (t < 96 && l < m) l3[c * 32 + l] = v;
        __syncthreads();
    }
    float dn0 = __fmul_rn(4.0f, sqrtf(l3[0]  / 799999.0f));
    float dn1 = __fmul_rn(4.0f, sqrtf(l3[32] / 799999.0f));
    float dn2 = __fmul_rn(4.0f, sqrtf(l3[64] / 799999.0f));
    __syncthreads();

    const unsigned int* gdwp = (const unsigned int*)(wsf + 8192);
    for (int i = t; i < NCELL * 32; i += 256) dwp[i] = gdwp[i];
    const float3* xT = (const float3*)(wsf + 16384) + (size_t)b * NPTS;
    if (t < 64) {
        if (t < nrem) {
            float3 v = xT[n0 + t];
            ctr[0][t] = v.x; ctr[1][t] = v.y; ctr[2][t] = v.z;
        }
    }
    const int* ib = idx + ((size_t)b * NPTS + n0) * KNN;
    __syncthreads();

    for (int i = t; i < nrem * KNN; i += 256) {
        int p = i >> 4;
        int jx = ib[i];
        float3 pj = xT[jx];
        float sx = __fsub_rn(pj.x, ctr[0][p]) / dn0;
        float sy = __fsub_rn(pj.y, ctr[1][p]) / dn1;
        float sz = __fsub_rn(pj.z, ctr[2][p]) / dn2;
        celllds[i] = (unsigned char)((to_cell32(sz) * 5 + to_cell32(sy)) * 5 + to_cell32(sx));
    }
    __syncthreads();

    int w = t >> 6, h = (t >> 5) & 1, u = t & 31;
    int o0 = 2 * u, o1 = 2 * u + 1;
    f32x2 cbv;
    cbv.x = cb[o0]; cbv.y = cb[o1];
    const unsigned short* gbp = g + (size_t)b * NPTS * C2;
    float* ob = out + (size_t)b * 128 * NPTS;

    #pragma unroll 1
    for (int chunk = 0; chunk < 4; ++chunk) {
        int pbase = chunk * 16;
        #pragma unroll 1
        for (int i = 0; i < 2; ++i) {
            int p = pbase + i * 8 + w * 2 + h;
            if (p < nrem) {
                const int* row = ib + p * KNN;
                unsigned int gnu = *(const unsigned int*)(gbp + (size_t)(n0 + p) * C2 + o0);
                unsigned int gvv[15];
                #pragma unroll
                for (int k = 0; k < 15; ++k) {
                    int jj = row[k + 1];
                    gvv[k] = *(const unsigned int*)(gbp + (size_t)jj * C2 + o0);
                }
                int cell0 = celllds[p * KNN];
                f32x2 k0v = unpk(dwp[cell0 * 32 + u]);
                f32x2 gn  = unpk(gnu);
                f32x2 ws = {0.f, 0.f}, gs = {0.f, 0.f}, sk = {0.f, 0.f};
                #pragma unroll
                for (int k = 0; k < 15; ++k) {
                    int cell = celllds[p * KNN + k + 1];
                    f32x2 dp = unpk(dwp[cell * 32 + u]);
                    f32x2 gv = unpk(gvv[k]);
                    ws += dp * gv;
                    gs += gv;
                    sk += dp;
                }
                f32x2 r1 = cbv * (k0v + sk) + gn * (k0v - sk) + ws;
                f32x2 r2 = cbv + 0.0625f * (gs - 14.0f * gn);
                int pl = p & 15;
                res[o0 * 17 + pl]        = r1.x;
                res[o1 * 17 + pl]        = r1.y;
                res[(64 + o0) * 17 + pl] = r2.x;
                res[(64 + o1) * 17 + pl] = r2.y;
            }
        }
        __syncthreads();
        int rl = t >> 4;
        int jn = t & 15;
        int ncol = nrem - pbase; if (ncol > 16) ncol = 16;
        if (jn < ncol) {
            for (int r2 = rl; r2 < 128; r2 += 16)
                __builtin_nontemporal_store(res[r2 * 17 + jn],
                                            &ob[(size_t)r2 * NPTS + n0 + pbase + jn]);
        }
        __syncthreads();
    }
}

extern "C" void kernel_launch(void* const* d_in, const int* in_sizes, int n_in,
                              void* d_out, int out_size, void* d_ws, size_t ws_size,
                              hipStream_t stream) {
    const float* xyz   = (const float*)d_in[0];
    const float* fea   = (const float*)d_in[1];
    const int*   knn   = (const int*)d_in[2];
    const float* convw = (const float*)d_in[3];
    const float* convb = (const float*)d_in[4];
    const float* convdw= (const float*)d_in[5];
    float* out = (float*)d_out;
    float* wsf = (float*)d_ws;
    unsigned short* g = (unsigned short*)(wsf + 327680);
    float3* rel3 = (float3*)out;     // 19.2 MB scratch, fully overwritten by kmain

    kprep <<<407, 256, 0, stream>>>(xyz, convdw, wsf);
    kfuse1<<<1564 + 512, 256, 0, stream>>>(knn, fea, convw, g, rel3, wsf);
    kpw2  <<<dim3(256, BATCH), 256, 0, stream>>>(rel3, wsf);
    kmain <<<1568, 256, 0, stream>>>(knn, convb, g, wsf, out);
}